// Round 4
// baseline (568.401 us; speedup 1.0000x reference)
//
#include <hip/hip_runtime.h>
#include <math.h>

#define NN 27
#define HID 128
#define SITERS 20
#define H1S 136          // f16 row stride for h1/H in LDS (272 B = 16B-aligned, bank-spread)

typedef float    v4    __attribute__((ext_vector_type(4)));
typedef _Float16 f16x8 __attribute__((ext_vector_type(8)));

// ---------------- Kernel 0: pre-swizzle W2 / protos into f16 MFMA fragment order ----------------
// B-frag (16x16x32): lane l holds B[k=kt*32+(l>>4)*8+j][n=nt*16+(l&15)], j=0..7 -> one 16B load/lane.
// A-frag:            lane l holds A[m=mt*16+(l&15)][k=kt*32+(l>>4)*8+j]          (m120-verified layout)
__global__ void k0_prep(const float* __restrict__ W2, const float* __restrict__ protos,
                        _Float16* __restrict__ Bsw, _Float16* __restrict__ Asw)
{
    int t0 = blockIdx.x * 256 + threadIdx.x;
    for (int idx = t0; idx < 4*8*64*8; idx += 8*256) {       // W2: kt(4) x nt(8) x lane x 8
        int j = idx & 7, l = (idx >> 3) & 63, nt = (idx >> 9) & 7, kt = idx >> 12;
        int k = kt*32 + (l >> 4)*8 + j, n = nt*16 + (l & 15);
        Bsw[idx] = (_Float16)W2[k*HID + n];
    }
    for (int idx = t0; idx < 2*4*64*8; idx += 8*256) {       // protos: mt(2) x kt(4) x lane x 8
        int j = idx & 7, l = (idx >> 3) & 63, kt = (idx >> 9) & 3, mt = idx >> 11;
        int k = kt*32 + (l >> 4)*8 + j, mm = mt*16 + (l & 15);
        Asw[idx] = (mm < NN) ? (_Float16)protos[mm*HID + k] : (_Float16)0.0f;
    }
}

// ---------------- Kernel 1: features + MLP(MFMA) + scores(MFMA) + SINKHORN, fully fused ----------
// block = 128 threads = 2 waves; wave w owns M-tile w (rows w*16..w*16+15) of both GEMMs.
// History: R6 MFMA rewrite; R7 LDS union (occ 39.5->88%); R8 Sinkhorn fusion; R9 despill
// (two-pass MFMA, WRITE 624->94MB, 592->471us). R10 (this round): REGISTER-RESIDENT SINKHORN.
// The old P7 ran ~4080 LDS-heavy wave-insts on wave 0 (wave 1 idle at the barrier) = ~65% of
// the block's instruction budget, VALU/DS issue-bound at 60% VALUBusy. The MFMA C-layout of P5
// already spreads P[i][j] over both waves (8 vals/thread, i=w*16+4g+r, j=nt2*16+c): row sums
// are 4x shfl_xor over c-bits, col sums are 2x shfl_xor over g-bits + one 64-float cross-wave
// LDS exchange per iter (ping-pong, 1 syncthreads). Deletes the 756-float LDS matrix, P6
// scatter, P8 LDS reads; both waves now share Sinkhorn work. Pads held at exact 0 via guarded
// reciprocals (no NaN). Eager col-scaling == reference op order (row-LSE, col-LSE per iter).
__global__ __launch_bounds__(128, 8) void k1_mlp(
    const float* __restrict__ A, const float* __restrict__ m,
    const float* __restrict__ tau_r,
    const float* __restrict__ ln1g, const float* __restrict__ ln1b,
    const float* __restrict__ W1, const float* __restrict__ b1,
    const float* __restrict__ b2,
    const float* __restrict__ ln2g, const float* __restrict__ ln2b,
    const _Float16* __restrict__ Bsw, const _Float16* __restrict__ Asw,
    float* __restrict__ out)
{
    __shared__ __align__(16) _Float16 sBuf[32 * H1S];          // 8704 B union buffer
    __shared__ __align__(16) float    sFeat[NN*4 + 4];

    float*    sA   = (float*)sBuf;     // 729 f32 = 2916 B, live P0..P1
    _Float16* sH1  = sBuf;             // h1 f16, rows 27..31 zero, live P2..P3
    _Float16* sH   = sBuf;             // normalized H f16, live P3b..P5
    float*    part = (float*)sBuf;     // Sinkhorn col-partials: 2 x [2][32] ping-pong, live P7

    const int b   = blockIdx.x;
    const int tid = threadIdx.x;
    const int l = tid & 63, w = tid >> 6;
    const int c = l & 15, g = l >> 4;
    const float* Ab = A + (size_t)b * (NN * NN);

    // ---- P0: stage A ----
    for (int i = tid; i < NN * NN; i += 128) sA[i] = Ab[i];
    __syncthreads();

    // ---- P1: features [log1p(rowsum), top1_offdiag, top2_offdiag, m] + LN1 ----
    if (tid < NN) {
        const int n = tid;
        float sum = 0.f, m1 = -1e30f, m2 = -1e30f;
        #pragma unroll
        for (int j = 0; j < NN; ++j) {
            float a = sA[n * NN + j];
            sum += a;
            float v = (j == n) ? 0.f : a;
            float nm1 = fmaxf(m1, v);
            m2 = fmaxf(m2, fminf(m1, v));
            m1 = nm1;
        }
        float f0 = log1pf(sum), f1 = m1, f2 = m2, f3 = m[(size_t)b * NN + n];
        float mu = 0.25f * (f0 + f1 + f2 + f3);
        float d0 = f0 - mu, d1 = f1 - mu, d2 = f2 - mu, d3 = f3 - mu;
        float var = 0.25f * (d0*d0 + d1*d1 + d2*d2 + d3*d3);
        float rs  = rsqrtf(var + 1e-5f);
        sFeat[n*4 + 0] = d0 * rs * ln1g[0] + ln1b[0];
        sFeat[n*4 + 1] = d1 * rs * ln1g[1] + ln1b[1];
        sFeat[n*4 + 2] = d2 * rs * ln1g[2] + ln1b[2];
        sFeat[n*4 + 3] = d3 * rs * ln1g[3] + ln1b[3];
    }
    __syncthreads();

    // ---- P2: h1 = relu(featLN @ W1 + b1) -> sH1 as f16; zero pad rows 27..31 ----
    {
        const float w0 = W1[tid], w1 = W1[HID + tid], w2 = W1[2*HID + tid], w3 = W1[3*HID + tid];
        const float bb = b1[tid];
        #pragma unroll 9
        for (int n = 0; n < NN; ++n) {
            v4 f = *(const v4*)&sFeat[n * 4];
            float v = fmaf(f[0], w0, fmaf(f[1], w1, fmaf(f[2], w2, fmaf(f[3], w3, bb))));
            sH1[n * H1S + tid] = (_Float16)fmaxf(v, 0.f);
        }
        #pragma unroll
        for (int n = NN; n < 32; ++n) sH1[n * H1S + tid] = (_Float16)0.f;
    }
    __syncthreads();

    // ---- P3: GEMM2 h2 = h1@W2, two-pass (despill). Wave w: rows w*16..+15, one acc tile. ----
    f16x8 af[4];
    #pragma unroll
    for (int kt = 0; kt < 4; ++kt)
        af[kt] = *(const f16x8*)&sH1[(w*16 + c) * H1S + kt*32 + g*8];

    const f16x8* Bv = (const f16x8*)Bsw;

    // pass 1: LN2 stats only
    float s4[4]  = {0.f, 0.f, 0.f, 0.f};
    float ss4[4] = {0.f, 0.f, 0.f, 0.f};
    #pragma unroll 1
    for (int nt = 0; nt < 8; ++nt) {
        v4 a = (v4)(0.f);
        #pragma unroll
        for (int kt = 0; kt < 4; ++kt)
            a = __builtin_amdgcn_mfma_f32_16x16x32_f16(af[kt], Bv[(kt*8 + nt)*64 + l], a, 0, 0, 0);
        float b2v = b2[nt*16 + c];
        #pragma unroll
        for (int r = 0; r < 4; ++r) {
            float v = a[r] + b2v;
            s4[r] += v; ss4[r] += v * v;
        }
    }
    float muv[4], rsv[4];
    #pragma unroll
    for (int r = 0; r < 4; ++r) {
        #pragma unroll
        for (int mask = 1; mask <= 8; mask <<= 1) {
            s4[r]  += __shfl_xor(s4[r],  mask);
            ss4[r] += __shfl_xor(ss4[r], mask);
        }
        float mu  = s4[r] * (1.0f / HID);
        float var = ss4[r] * (1.0f / HID) - mu * mu;
        muv[r] = mu;
        rsv[r] = rsqrtf(var + 1e-5f);
    }

    // pass 2: recompute identical tiles, fuse bias + LN2, store f16 H (own rows only)
    #pragma unroll 1
    for (int nt = 0; nt < 8; ++nt) {
        v4 a = (v4)(0.f);
        #pragma unroll
        for (int kt = 0; kt < 4; ++kt)
            a = __builtin_amdgcn_mfma_f32_16x16x32_f16(af[kt], Bv[(kt*8 + nt)*64 + l], a, 0, 0, 0);
        int col = nt*16 + c;
        float b2v = b2[col], g2 = ln2g[col], bb = ln2b[col];
        #pragma unroll
        for (int r = 0; r < 4; ++r) {
            float hv = (a[r] + b2v - muv[r]) * rsv[r] * g2 + bb;
            sH[(w*16 + 4*g + r) * H1S + col] = (_Float16)hv;
        }
    }
    __syncthreads();   // all H rows written (both waves) before P5 B-frag reads

    // ---- P5: scores[i][j] = protos[i] . H[j] via MFMA. Wave w: i-tile w. ----
    v4 acc2[2];
    {
        const f16x8* Av = (const f16x8*)Asw;
        acc2[0] = (v4)(0.f); acc2[1] = (v4)(0.f);
        #pragma unroll
        for (int kt = 0; kt < 4; ++kt) {
            f16x8 pa  = Av[(w*4 + kt)*64 + l];
            f16x8 b0  = *(const f16x8*)&sH[(c)      * H1S + kt*32 + g*8];
            f16x8 b1f = *(const f16x8*)&sH[(16 + c) * H1S + kt*32 + g*8];
            acc2[0] = __builtin_amdgcn_mfma_f32_16x16x32_f16(pa, b0,  acc2[0], 0, 0, 0);
            acc2[1] = __builtin_amdgcn_mfma_f32_16x16x32_f16(pa, b1f, acc2[1], 0, 0, 0);
        }
    }
    __syncthreads();   // both waves' sH reads complete before part[] overwrites the union buffer

    // ---- P6: P = exp(score/tau) IN REGISTERS (C-layout: i=w*16+4g+r, j0=c, j1=16+c) ----
    const int i0 = w*16 + 4*g;
    const int j1 = 16 + c;               // j0 = c < 16 < NN always valid
    float p0[4], p1[4];
    {
        const float inv_tau = 1.0f / tau_r[0];
        #pragma unroll
        for (int r = 0; r < 4; ++r) {
            bool iok = (i0 + r) < NN;
            p0[r] = iok ? __expf(acc2[0][r] * inv_tau) : 0.f;
            p1[r] = (iok && j1 < NN) ? __expf(acc2[1][r] * inv_tau) : 0.f;
        }
    }

    // ---- P7: 20-iter Sinkhorn in registers. Row: shfl over c-bits. Col: shfl over g-bits
    //          + one 64-float cross-wave LDS exchange (ping-pong, 1 syncthreads/iter). ----
    for (int it = 0; it < SITERS; ++it) {
        // row normalize (reference: LSE over axis=-1 first)
        #pragma unroll
        for (int r = 0; r < 4; ++r) {
            float s = p0[r] + p1[r];
            s += __shfl_xor(s, 1);
            s += __shfl_xor(s, 2);
            s += __shfl_xor(s, 4);
            s += __shfl_xor(s, 8);
            float rho = ((i0 + r) < NN) ? (1.0f / s) : 0.f;   // pad rows stay exactly 0
            p0[r] *= rho;
            p1[r] *= rho;
        }
        // col normalize (axis=-2): in-thread r-sum, shfl over g, cross-wave via LDS
        float t0 = (p0[0] + p0[1]) + (p0[2] + p0[3]);
        float t1 = (p1[0] + p1[1]) + (p1[2] + p1[3]);
        t0 += __shfl_xor(t0, 16);  t0 += __shfl_xor(t0, 32);
        t1 += __shfl_xor(t1, 16);  t1 += __shfl_xor(t1, 32);
        float* pb = part + (it & 1) * 64;
        if (g == 0) {
            pb[w*32 + c]      = t0;
            pb[w*32 + 16 + c] = t1;
        }
        __syncthreads();
        float cs0 = t0 + pb[(w^1)*32 + c];
        float cs1 = t1 + pb[(w^1)*32 + 16 + c];
        float rc0 = 1.0f / cs0;                          // j0 < NN always, cs0 > 0
        float rc1 = (j1 < NN) ? (1.0f / cs1) : 0.f;      // pad cols stay exactly 0
        #pragma unroll
        for (int r = 0; r < 4; ++r) {
            p0[r] *= rc0;
            p1[r] *= rc1;
        }
    }

    // ---- P8: store P straight from registers (16-lane 64B-contiguous runs per (i,nt2)) ----
    {
        float* ob = out + (size_t)b * (NN * NN);
        #pragma unroll
        for (int r = 0; r < 4; ++r) {
            int i = i0 + r;
            if (i < NN) {
                ob[i * NN + c] = p0[r];
                if (j1 < NN) ob[i * NN + j1] = p1[r];
            }
        }
    }
}

extern "C" void kernel_launch(void* const* d_in, const int* in_sizes, int n_in,
                              void* d_out, int out_size, void* d_ws, size_t ws_size,
                              hipStream_t stream) {
    const float* A      = (const float*)d_in[0];
    const float* m      = (const float*)d_in[1];
    const float* tau_r  = (const float*)d_in[2];
    const float* ln1g   = (const float*)d_in[3];
    const float* ln1b   = (const float*)d_in[4];
    const float* W1     = (const float*)d_in[5];
    const float* b1     = (const float*)d_in[6];
    const float* W2     = (const float*)d_in[7];
    const float* b2     = (const float*)d_in[8];
    const float* ln2g   = (const float*)d_in[9];
    const float* ln2b   = (const float*)d_in[10];
    const float* protos = (const float*)d_in[11];
    float* out = (float*)d_out;

    const int B = in_sizes[0] / (NN * NN);

    _Float16* Bsw = (_Float16*)d_ws;                         // 16384 f16 = 32 KB
    _Float16* Asw = (_Float16*)((char*)d_ws + 32768);        //  4096 f16 =  8 KB

    k0_prep<<<8, 256, 0, stream>>>(W2, protos, Bsw, Asw);
    k1_mlp<<<B, 128, 0, stream>>>(A, m, tau_r, ln1g, ln1b, W1, b1, b2,
                                  ln2g, ln2b, Bsw, Asw, out);
}

// Round 5
// 547.652 us; speedup vs baseline: 1.0379x; 1.0379x over previous
//
#include <hip/hip_runtime.h>
#include <math.h>

#define NN 27
#define HID 128
#define SITERS 20
#define H1S 136          // f16 row stride for h1/H in LDS (272 B = 16B-aligned, bank-spread)

typedef float    v4    __attribute__((ext_vector_type(4)));
typedef _Float16 f16x8 __attribute__((ext_vector_type(8)));

// ---------------- Kernel 0: pre-swizzle W2 / protos into f16 MFMA fragment order ----------------
// B-frag (16x16x32): lane l holds B[k=kt*32+(l>>4)*8+j][n=nt*16+(l&15)], j=0..7 -> one 16B load/lane.
// A-frag:            lane l holds A[m=mt*16+(l&15)][k=kt*32+(l>>4)*8+j]          (m120-verified layout)
__global__ void k0_prep(const float* __restrict__ W2, const float* __restrict__ protos,
                        _Float16* __restrict__ Bsw, _Float16* __restrict__ Asw)
{
    int t0 = blockIdx.x * 256 + threadIdx.x;
    for (int idx = t0; idx < 4*8*64*8; idx += 8*256) {       // W2: kt(4) x nt(8) x lane x 8
        int j = idx & 7, l = (idx >> 3) & 63, nt = (idx >> 9) & 7, kt = idx >> 12;
        int k = kt*32 + (l >> 4)*8 + j, n = nt*16 + (l & 15);
        Bsw[idx] = (_Float16)W2[k*HID + n];
    }
    for (int idx = t0; idx < 2*4*64*8; idx += 8*256) {       // protos: mt(2) x kt(4) x lane x 8
        int j = idx & 7, l = (idx >> 3) & 63, kt = (idx >> 9) & 3, mt = idx >> 11;
        int k = kt*32 + (l >> 4)*8 + j, mm = mt*16 + (l & 15);
        Asw[idx] = (mm < NN) ? (_Float16)protos[mm*HID + k] : (_Float16)0.0f;
    }
}

// ---------------- Kernel 1: features + MLP(MFMA) + scores(MFMA) + SINKHORN, fully fused ----------
// block = 128 threads = 2 waves; wave w owns M-tile w (rows w*16..w*16+15) of both GEMMs.
// History: R6 MFMA rewrite; R7 LDS union (occ 39.5->88%); R8 Sinkhorn fusion; R9 despill
// (two-pass MFMA, WRITE 624->94MB); R10 register-resident Sinkhorn (neutral: structure right,
// but division count went 2->6 per iter; IEEE div = ~8-inst v_div sequence + VCC serialization,
// ~1000 insts/thread, cancelling the LDS-Sinkhorn removal -> VALUBusy 87%, issue-bound).
// R11 (this round): kill the divisions. All six per-iter 1/x -> __builtin_amdgcn_rcpf
// (1x v_rcp_f32, ~1ulp; accumulated err ~1e-5 << the 2.4e-4 f16-GEMM error). Pad guards are
// branch-free: rho = rcpf(s + pad) * mask with precomputed pad/mask in {0,1} (rcpf(1)=1, x0 = 0
// exactly; no inf*0 NaN, no per-iter cndmask/VCC).
__global__ __launch_bounds__(128, 8) void k1_mlp(
    const float* __restrict__ A, const float* __restrict__ m,
    const float* __restrict__ tau_r,
    const float* __restrict__ ln1g, const float* __restrict__ ln1b,
    const float* __restrict__ W1, const float* __restrict__ b1,
    const float* __restrict__ b2,
    const float* __restrict__ ln2g, const float* __restrict__ ln2b,
    const _Float16* __restrict__ Bsw, const _Float16* __restrict__ Asw,
    float* __restrict__ out)
{
    __shared__ __align__(16) _Float16 sBuf[32 * H1S];          // 8704 B union buffer
    __shared__ __align__(16) float    sFeat[NN*4 + 4];

    float*    sA   = (float*)sBuf;     // 729 f32 = 2916 B, live P0..P1
    _Float16* sH1  = sBuf;             // h1 f16, rows 27..31 zero, live P2..P3
    _Float16* sH   = sBuf;             // normalized H f16, live P3b..P5
    float*    part = (float*)sBuf;     // Sinkhorn col-partials: 2 x [2][32] ping-pong, live P7

    const int b   = blockIdx.x;
    const int tid = threadIdx.x;
    const int l = tid & 63, w = tid >> 6;
    const int c = l & 15, g = l >> 4;
    const float* Ab = A + (size_t)b * (NN * NN);

    // ---- P0: stage A ----
    for (int i = tid; i < NN * NN; i += 128) sA[i] = Ab[i];
    __syncthreads();

    // ---- P1: features [log1p(rowsum), top1_offdiag, top2_offdiag, m] + LN1 ----
    if (tid < NN) {
        const int n = tid;
        float sum = 0.f, m1 = -1e30f, m2 = -1e30f;
        #pragma unroll
        for (int j = 0; j < NN; ++j) {
            float a = sA[n * NN + j];
            sum += a;
            float v = (j == n) ? 0.f : a;
            float nm1 = fmaxf(m1, v);
            m2 = fmaxf(m2, fminf(m1, v));
            m1 = nm1;
        }
        float f0 = log1pf(sum), f1 = m1, f2 = m2, f3 = m[(size_t)b * NN + n];
        float mu = 0.25f * (f0 + f1 + f2 + f3);
        float d0 = f0 - mu, d1 = f1 - mu, d2 = f2 - mu, d3 = f3 - mu;
        float var = 0.25f * (d0*d0 + d1*d1 + d2*d2 + d3*d3);
        float rs  = rsqrtf(var + 1e-5f);
        sFeat[n*4 + 0] = d0 * rs * ln1g[0] + ln1b[0];
        sFeat[n*4 + 1] = d1 * rs * ln1g[1] + ln1b[1];
        sFeat[n*4 + 2] = d2 * rs * ln1g[2] + ln1b[2];
        sFeat[n*4 + 3] = d3 * rs * ln1g[3] + ln1b[3];
    }
    __syncthreads();

    // ---- P2: h1 = relu(featLN @ W1 + b1) -> sH1 as f16; zero pad rows 27..31 ----
    {
        const float w0 = W1[tid], w1 = W1[HID + tid], w2 = W1[2*HID + tid], w3 = W1[3*HID + tid];
        const float bb = b1[tid];
        #pragma unroll 9
        for (int n = 0; n < NN; ++n) {
            v4 f = *(const v4*)&sFeat[n * 4];
            float v = fmaf(f[0], w0, fmaf(f[1], w1, fmaf(f[2], w2, fmaf(f[3], w3, bb))));
            sH1[n * H1S + tid] = (_Float16)fmaxf(v, 0.f);
        }
        #pragma unroll
        for (int n = NN; n < 32; ++n) sH1[n * H1S + tid] = (_Float16)0.f;
    }
    __syncthreads();

    // ---- P3: GEMM2 h2 = h1@W2, two-pass (despill). Wave w: rows w*16..+15, one acc tile. ----
    f16x8 af[4];
    #pragma unroll
    for (int kt = 0; kt < 4; ++kt)
        af[kt] = *(const f16x8*)&sH1[(w*16 + c) * H1S + kt*32 + g*8];

    const f16x8* Bv = (const f16x8*)Bsw;

    // pass 1: LN2 stats only
    float s4[4]  = {0.f, 0.f, 0.f, 0.f};
    float ss4[4] = {0.f, 0.f, 0.f, 0.f};
    #pragma unroll 1
    for (int nt = 0; nt < 8; ++nt) {
        v4 a = (v4)(0.f);
        #pragma unroll
        for (int kt = 0; kt < 4; ++kt)
            a = __builtin_amdgcn_mfma_f32_16x16x32_f16(af[kt], Bv[(kt*8 + nt)*64 + l], a, 0, 0, 0);
        float b2v = b2[nt*16 + c];
        #pragma unroll
        for (int r = 0; r < 4; ++r) {
            float v = a[r] + b2v;
            s4[r] += v; ss4[r] += v * v;
        }
    }
    float muv[4], rsv[4];
    #pragma unroll
    for (int r = 0; r < 4; ++r) {
        #pragma unroll
        for (int mask = 1; mask <= 8; mask <<= 1) {
            s4[r]  += __shfl_xor(s4[r],  mask);
            ss4[r] += __shfl_xor(ss4[r], mask);
        }
        float mu  = s4[r] * (1.0f / HID);
        float var = ss4[r] * (1.0f / HID) - mu * mu;
        muv[r] = mu;
        rsv[r] = rsqrtf(var + 1e-5f);
    }

    // pass 2: recompute identical tiles, fuse bias + LN2, store f16 H (own rows only)
    #pragma unroll 1
    for (int nt = 0; nt < 8; ++nt) {
        v4 a = (v4)(0.f);
        #pragma unroll
        for (int kt = 0; kt < 4; ++kt)
            a = __builtin_amdgcn_mfma_f32_16x16x32_f16(af[kt], Bv[(kt*8 + nt)*64 + l], a, 0, 0, 0);
        int col = nt*16 + c;
        float b2v = b2[col], g2 = ln2g[col], bb = ln2b[col];
        #pragma unroll
        for (int r = 0; r < 4; ++r) {
            float hv = (a[r] + b2v - muv[r]) * rsv[r] * g2 + bb;
            sH[(w*16 + 4*g + r) * H1S + col] = (_Float16)hv;
        }
    }
    __syncthreads();   // all H rows written (both waves) before P5 B-frag reads

    // ---- P5: scores[i][j] = protos[i] . H[j] via MFMA. Wave w: i-tile w. ----
    v4 acc2[2];
    {
        const f16x8* Av = (const f16x8*)Asw;
        acc2[0] = (v4)(0.f); acc2[1] = (v4)(0.f);
        #pragma unroll
        for (int kt = 0; kt < 4; ++kt) {
            f16x8 pa  = Av[(w*4 + kt)*64 + l];
            f16x8 b0  = *(const f16x8*)&sH[(c)      * H1S + kt*32 + g*8];
            f16x8 b1f = *(const f16x8*)&sH[(16 + c) * H1S + kt*32 + g*8];
            acc2[0] = __builtin_amdgcn_mfma_f32_16x16x32_f16(pa, b0,  acc2[0], 0, 0, 0);
            acc2[1] = __builtin_amdgcn_mfma_f32_16x16x32_f16(pa, b1f, acc2[1], 0, 0, 0);
        }
    }
    __syncthreads();   // both waves' sH reads complete before part[] overwrites the union buffer

    // ---- P6: P = exp(score/tau) IN REGISTERS (C-layout: i=w*16+4g+r, j0=c, j1=16+c) ----
    const int i0 = w*16 + 4*g;
    const int j1 = 16 + c;               // j0 = c < 16 < NN always valid
    float p0[4], p1[4];
    // branch-free pad masks: mask in {1,0}, pad = 1-mask (rcpf(0+1)=1, *0 = exact 0; no NaN)
    float rowm[4], rowp[4];
    #pragma unroll
    for (int r = 0; r < 4; ++r) {
        rowm[r] = ((i0 + r) < NN) ? 1.f : 0.f;
        rowp[r] = 1.f - rowm[r];
    }
    const float colm1 = (j1 < NN) ? 1.f : 0.f;
    const float colp1 = 1.f - colm1;
    {
        const float inv_tau = 1.0f / tau_r[0];
        #pragma unroll
        for (int r = 0; r < 4; ++r) {
            bool iok = (i0 + r) < NN;
            p0[r] = iok ? __expf(acc2[0][r] * inv_tau) : 0.f;
            p1[r] = (iok && j1 < NN) ? __expf(acc2[1][r] * inv_tau) : 0.f;
        }
    }

    // ---- P7: 20-iter Sinkhorn in registers. Row: shfl over c-bits. Col: shfl over g-bits
    //          + one 64-float cross-wave LDS exchange (ping-pong, 1 syncthreads/iter).
    //          All reciprocals are single v_rcp_f32 (rcpf) — no IEEE div sequences. ----
    for (int it = 0; it < SITERS; ++it) {
        // row normalize (reference: LSE over axis=-1 first)
        #pragma unroll
        for (int r = 0; r < 4; ++r) {
            float s = p0[r] + p1[r];
            s += __shfl_xor(s, 1);
            s += __shfl_xor(s, 2);
            s += __shfl_xor(s, 4);
            s += __shfl_xor(s, 8);
            float rho = __builtin_amdgcn_rcpf(s + rowp[r]) * rowm[r];   // pad rows stay exact 0
            p0[r] *= rho;
            p1[r] *= rho;
        }
        // col normalize (axis=-2): in-thread r-sum, shfl over g, cross-wave via LDS
        float t0 = (p0[0] + p0[1]) + (p0[2] + p0[3]);
        float t1 = (p1[0] + p1[1]) + (p1[2] + p1[3]);
        t0 += __shfl_xor(t0, 16);  t0 += __shfl_xor(t0, 32);
        t1 += __shfl_xor(t1, 16);  t1 += __shfl_xor(t1, 32);
        float* pb = part + (it & 1) * 64;
        if (g == 0) {
            pb[w*32 + c]      = t0;
            pb[w*32 + 16 + c] = t1;
        }
        __syncthreads();
        float cs0 = t0 + pb[(w^1)*32 + c];
        float cs1 = t1 + pb[(w^1)*32 + 16 + c];
        float rc0 = __builtin_amdgcn_rcpf(cs0);                  // j0 < NN always, cs0 > 0
        float rc1 = __builtin_amdgcn_rcpf(cs1 + colp1) * colm1;  // pad cols stay exact 0
        #pragma unroll
        for (int r = 0; r < 4; ++r) {
            p0[r] *= rc0;
            p1[r] *= rc1;
        }
    }

    // ---- P8: store P straight from registers (16-lane 64B-contiguous runs per (i,nt2)) ----
    {
        float* ob = out + (size_t)b * (NN * NN);
        #pragma unroll
        for (int r = 0; r < 4; ++r) {
            int i = i0 + r;
            if (i < NN) {
                ob[i * NN + c] = p0[r];
                if (j1 < NN) ob[i * NN + j1] = p1[r];
            }
        }
    }
}

extern "C" void kernel_launch(void* const* d_in, const int* in_sizes, int n_in,
                              void* d_out, int out_size, void* d_ws, size_t ws_size,
                              hipStream_t stream) {
    const float* A      = (const float*)d_in[0];
    const float* m      = (const float*)d_in[1];
    const float* tau_r  = (const float*)d_in[2];
    const float* ln1g   = (const float*)d_in[3];
    const float* ln1b   = (const float*)d_in[4];
    const float* W1     = (const float*)d_in[5];
    const float* b1     = (const float*)d_in[6];
    const float* W2     = (const float*)d_in[7];
    const float* b2     = (const float*)d_in[8];
    const float* ln2g   = (const float*)d_in[9];
    const float* ln2b   = (const float*)d_in[10];
    const float* protos = (const float*)d_in[11];
    float* out = (float*)d_out;

    const int B = in_sizes[0] / (NN * NN);

    _Float16* Bsw = (_Float16*)d_ws;                         // 16384 f16 = 32 KB
    _Float16* Asw = (_Float16*)((char*)d_ws + 32768);        //  4096 f16 =  8 KB

    k0_prep<<<8, 256, 0, stream>>>(W2, protos, Bsw, Asw);
    k1_mlp<<<B, 128, 0, stream>>>(A, m, tau_r, ln1g, ln1b, W1, b1, b2,
                                  ln2g, ln2b, Bsw, Asw, out);
}

// Round 6
// 514.033 us; speedup vs baseline: 1.1058x; 1.0654x over previous
//
#include <hip/hip_runtime.h>
#include <math.h>

#define NN 27
#define HID 128
#define SITERS 20
#define H1S 136          // f16 row stride for h1/H in LDS (272 B = 16B-aligned, bank-spread)

typedef float    v4    __attribute__((ext_vector_type(4)));
typedef _Float16 f16x8 __attribute__((ext_vector_type(8)));

// ---------------- Kernel 0: pre-swizzle W2 / protos into f16 MFMA fragment order ----------------
// B-frag (16x16x32): lane l holds B[k=kt*32+(l>>4)*8+j][n=nt*16+(l&15)], j=0..7 -> one 16B load/lane.
// A-frag:            lane l holds A[m=mt*16+(l&15)][k=kt*32+(l>>4)*8+j]          (m120-verified layout)
__global__ void k0_prep(const float* __restrict__ W2, const float* __restrict__ protos,
                        _Float16* __restrict__ Bsw, _Float16* __restrict__ Asw)
{
    int t0 = blockIdx.x * 256 + threadIdx.x;
    for (int idx = t0; idx < 4*8*64*8; idx += 8*256) {       // W2: kt(4) x nt(8) x lane x 8
        int j = idx & 7, l = (idx >> 3) & 63, nt = (idx >> 9) & 7, kt = idx >> 12;
        int k = kt*32 + (l >> 4)*8 + j, n = nt*16 + (l & 15);
        Bsw[idx] = (_Float16)W2[k*HID + n];
    }
    for (int idx = t0; idx < 2*4*64*8; idx += 8*256) {       // protos: mt(2) x kt(4) x lane x 8
        int j = idx & 7, l = (idx >> 3) & 63, kt = (idx >> 9) & 3, mt = idx >> 11;
        int k = kt*32 + (l >> 4)*8 + j, mm = mt*16 + (l & 15);
        Asw[idx] = (mm < NN) ? (_Float16)protos[mm*HID + k] : (_Float16)0.0f;
    }
}

// ---------------- Kernel 1: ONE WAVE PER MATRIX — features+MLP+scores+Sinkhorn, barrier-free ----
// History: R6 MFMA rewrite; R7 LDS union (occ cap); R8 Sinkhorn fusion; R9 despill (two-pass
// MFMA); R10 register Sinkhorn; R11 rcpf (VALUBusy 87->60 -> latency/sync-bound: 26 syncthreads
// + per-iter LDS exchange). R12 (this round): 64-thread blocks, whole matrix per wave.
// - All 6 phase syncthreads -> free wave_barrier() fences (intra-wave LDS is in-order; k2-proven).
// - Sinkhorn col sums collapse in-thread over mt,r + 2 shfls: the cross-wave LDS exchange and
//   its 20 syncthreads are GONE. Zero barriers anywhere.
// - Bv fragments loaded once per (kt,nt), reused for both mt: halves fragment loads per matrix.
// - launch_bounds(64,4): VGPR cap 128 (no spill; peak ~95), LDS 9216 -> ~16 blocks/CU.
//   Occupancy halves vs R11 but waves are barrier-free straight-line streams (R1 showed waves
//   beyond ~14/CU add little; latency-chains + rendezvous were the cost).
__global__ __launch_bounds__(64, 4) void k1_mlp(
    const float* __restrict__ A, const float* __restrict__ m,
    const float* __restrict__ tau_r,
    const float* __restrict__ ln1g, const float* __restrict__ ln1b,
    const float* __restrict__ W1, const float* __restrict__ b1,
    const float* __restrict__ b2,
    const float* __restrict__ ln2g, const float* __restrict__ ln2b,
    const _Float16* __restrict__ Bsw, const _Float16* __restrict__ Asw,
    float* __restrict__ out)
{
    __shared__ __align__(16) _Float16 sBuf[32 * H1S];          // 8704 B union buffer
    __shared__ __align__(16) float    sFeat[NN*4 + 4];

    float*    sA   = (float*)sBuf;     // 729 f32 = 2916 B, live P0..P1
    _Float16* sH1  = sBuf;             // h1 f16, rows 27..31 zero, live P2..P3
    _Float16* sH   = sBuf;             // normalized H f16, live P3b..P5

    const int b = blockIdx.x;
    const int l = threadIdx.x;         // 0..63, one wave
    const int c = l & 15, g = l >> 4;
    const float* Ab = A + (size_t)b * (NN * NN);

    // ---- P0: stage A ----
    for (int i = l; i < NN * NN; i += 64) sA[i] = Ab[i];
    __builtin_amdgcn_wave_barrier();   // intra-wave LDS ordering: compiler fence suffices

    // ---- P1: features [log1p(rowsum), top1_offdiag, top2_offdiag, m] + LN1 (lanes 0..26) ----
    if (l < NN) {
        const int n = l;
        float sum = 0.f, m1 = -1e30f, m2 = -1e30f;
        #pragma unroll
        for (int j = 0; j < NN; ++j) {
            float a = sA[n * NN + j];
            sum += a;
            float v = (j == n) ? 0.f : a;
            float nm1 = fmaxf(m1, v);
            m2 = fmaxf(m2, fminf(m1, v));
            m1 = nm1;
        }
        float f0 = log1pf(sum), f1 = m1, f2 = m2, f3 = m[(size_t)b * NN + n];
        float mu = 0.25f * (f0 + f1 + f2 + f3);
        float d0 = f0 - mu, d1 = f1 - mu, d2 = f2 - mu, d3 = f3 - mu;
        float var = 0.25f * (d0*d0 + d1*d1 + d2*d2 + d3*d3);
        float rs  = rsqrtf(var + 1e-5f);
        sFeat[n*4 + 0] = d0 * rs * ln1g[0] + ln1b[0];
        sFeat[n*4 + 1] = d1 * rs * ln1g[1] + ln1b[1];
        sFeat[n*4 + 2] = d2 * rs * ln1g[2] + ln1b[2];
        sFeat[n*4 + 3] = d3 * rs * ln1g[3] + ln1b[3];
    }
    __builtin_amdgcn_wave_barrier();

    // ---- P2: h1 = relu(featLN @ W1 + b1) -> sH1 as f16; 2 cols/thread; zero pad rows ----
    {
        const float w0a = W1[l],      w1a = W1[HID + l],      w2a = W1[2*HID + l],      w3a = W1[3*HID + l];
        const float w0b = W1[64 + l], w1b = W1[HID + 64 + l], w2b = W1[2*HID + 64 + l], w3b = W1[3*HID + 64 + l];
        const float bba = b1[l], bbb = b1[64 + l];
        #pragma unroll 9
        for (int n = 0; n < NN; ++n) {
            v4 f = *(const v4*)&sFeat[n * 4];
            float va = fmaf(f[0], w0a, fmaf(f[1], w1a, fmaf(f[2], w2a, fmaf(f[3], w3a, bba))));
            float vb = fmaf(f[0], w0b, fmaf(f[1], w1b, fmaf(f[2], w2b, fmaf(f[3], w3b, bbb))));
            sH1[n * H1S + l]      = (_Float16)fmaxf(va, 0.f);
            sH1[n * H1S + 64 + l] = (_Float16)fmaxf(vb, 0.f);
        }
        #pragma unroll
        for (int n = NN; n < 32; ++n) {
            sH1[n * H1S + l]      = (_Float16)0.f;
            sH1[n * H1S + 64 + l] = (_Float16)0.f;
        }
    }
    __builtin_amdgcn_wave_barrier();

    // ---- P3: GEMM2 h2 = h1@W2, two-pass (despill), whole M=32 in this wave (mt 0..1) ----
    f16x8 af[2][4];
    #pragma unroll
    for (int mt = 0; mt < 2; ++mt)
        #pragma unroll
        for (int kt = 0; kt < 4; ++kt)
            af[mt][kt] = *(const f16x8*)&sH1[(mt*16 + c) * H1S + kt*32 + g*8];

    const f16x8* Bv = (const f16x8*)Bsw;

    // pass 1: LN2 stats only (one bf[4] set per nt, shared by both mt)
    float s4[2][4]  = {{0.f,0.f,0.f,0.f},{0.f,0.f,0.f,0.f}};
    float ss4[2][4] = {{0.f,0.f,0.f,0.f},{0.f,0.f,0.f,0.f}};
    #pragma unroll 1
    for (int nt = 0; nt < 8; ++nt) {
        f16x8 bf[4];
        #pragma unroll
        for (int kt = 0; kt < 4; ++kt) bf[kt] = Bv[(kt*8 + nt)*64 + l];
        float b2v = b2[nt*16 + c];
        #pragma unroll
        for (int mt = 0; mt < 2; ++mt) {
            v4 a = (v4)(0.f);
            #pragma unroll
            for (int kt = 0; kt < 4; ++kt)
                a = __builtin_amdgcn_mfma_f32_16x16x32_f16(af[mt][kt], bf[kt], a, 0, 0, 0);
            #pragma unroll
            for (int r = 0; r < 4; ++r) {
                float v = a[r] + b2v;
                s4[mt][r] += v; ss4[mt][r] += v * v;
            }
        }
    }
    float muv[2][4], rsv[2][4];
    #pragma unroll
    for (int mt = 0; mt < 2; ++mt)
        #pragma unroll
        for (int r = 0; r < 4; ++r) {
            #pragma unroll
            for (int mask = 1; mask <= 8; mask <<= 1) {
                s4[mt][r]  += __shfl_xor(s4[mt][r],  mask);
                ss4[mt][r] += __shfl_xor(ss4[mt][r], mask);
            }
            float mu  = s4[mt][r] * (1.0f / HID);
            float var = ss4[mt][r] * (1.0f / HID) - mu * mu;
            muv[mt][r] = mu;
            rsv[mt][r] = rsqrtf(var + 1e-5f);
        }

    // pass 2: recompute identical tiles, fuse bias + LN2, store f16 H (all 32 rows, own wave)
    #pragma unroll 1
    for (int nt = 0; nt < 8; ++nt) {
        f16x8 bf[4];
        #pragma unroll
        for (int kt = 0; kt < 4; ++kt) bf[kt] = Bv[(kt*8 + nt)*64 + l];
        int col = nt*16 + c;
        float b2v = b2[col], g2 = ln2g[col], bb = ln2b[col];
        #pragma unroll
        for (int mt = 0; mt < 2; ++mt) {
            v4 a = (v4)(0.f);
            #pragma unroll
            for (int kt = 0; kt < 4; ++kt)
                a = __builtin_amdgcn_mfma_f32_16x16x32_f16(af[mt][kt], bf[kt], a, 0, 0, 0);
            #pragma unroll
            for (int r = 0; r < 4; ++r) {
                float hv = (a[r] + b2v - muv[mt][r]) * rsv[mt][r] * g2 + bb;
                sH[(mt*16 + 4*g + r) * H1S + col] = (_Float16)hv;
            }
        }
    }
    __builtin_amdgcn_wave_barrier();   // sH writes before B-frag reads (intra-wave, in-order)

    // ---- P5: scores[i][j] = protos[i] . H[j] via MFMA; C tiles mt(2) x nt2(2) ----
    v4 acc2[2][2];
    acc2[0][0] = (v4)(0.f); acc2[0][1] = (v4)(0.f);
    acc2[1][0] = (v4)(0.f); acc2[1][1] = (v4)(0.f);
    {
        const f16x8* Av = (const f16x8*)Asw;
        #pragma unroll
        for (int kt = 0; kt < 4; ++kt) {
            f16x8 b0  = *(const f16x8*)&sH[(c)      * H1S + kt*32 + g*8];
            f16x8 b1f = *(const f16x8*)&sH[(16 + c) * H1S + kt*32 + g*8];
            f16x8 pa0 = Av[(0*4 + kt)*64 + l];
            f16x8 pa1 = Av[(1*4 + kt)*64 + l];
            acc2[0][0] = __builtin_amdgcn_mfma_f32_16x16x32_f16(pa0, b0,  acc2[0][0], 0, 0, 0);
            acc2[0][1] = __builtin_amdgcn_mfma_f32_16x16x32_f16(pa0, b1f, acc2[0][1], 0, 0, 0);
            acc2[1][0] = __builtin_amdgcn_mfma_f32_16x16x32_f16(pa1, b0,  acc2[1][0], 0, 0, 0);
            acc2[1][1] = __builtin_amdgcn_mfma_f32_16x16x32_f16(pa1, b1f, acc2[1][1], 0, 0, 0);
        }
    }

    // ---- P6: P = exp(score/tau) in registers. i = mt*16+4g+r, j0 = c, j1 = 16+c ----
    // mt=0 rows (i<=15<27) always valid; mt=1 rows need i<27; col j1 needs c<11.
    float p[2][2][4];
    float rowm1[4], rowp1[4];
    #pragma unroll
    for (int r = 0; r < 4; ++r) {
        rowm1[r] = ((16 + 4*g + r) < NN) ? 1.f : 0.f;
        rowp1[r] = 1.f - rowm1[r];
    }
    const float colm1 = ((16 + c) < NN) ? 1.f : 0.f;
    const float colp1 = 1.f - colm1;
    {
        const float inv_tau = 1.0f / tau_r[0];
        #pragma unroll
        for (int r = 0; r < 4; ++r) {
            p[0][0][r] = __expf(acc2[0][0][r] * inv_tau);
            p[0][1][r] = (colm1 != 0.f) ? __expf(acc2[0][1][r] * inv_tau) : 0.f;
            bool iok = (16 + 4*g + r) < NN;
            p[1][0][r] = iok ? __expf(acc2[1][0][r] * inv_tau) : 0.f;
            p[1][1][r] = (iok && colm1 != 0.f) ? __expf(acc2[1][1][r] * inv_tau) : 0.f;
        }
    }

    // ---- P7: 20-iter Sinkhorn, fully wave-local. Rows: shfl over c-bits. Cols: in-thread
    //          over (mt,r) + shfl over g-bits. No LDS, no barriers. rcpf throughout. ----
    for (int it = 0; it < SITERS; ++it) {
        // row normalize (axis=-1 first, as reference)
        #pragma unroll
        for (int r = 0; r < 4; ++r) {           // mt=0: always valid
            float s = p[0][0][r] + p[0][1][r];
            s += __shfl_xor(s, 1);
            s += __shfl_xor(s, 2);
            s += __shfl_xor(s, 4);
            s += __shfl_xor(s, 8);
            float rho = __builtin_amdgcn_rcpf(s);
            p[0][0][r] *= rho;
            p[0][1][r] *= rho;
        }
        #pragma unroll
        for (int r = 0; r < 4; ++r) {           // mt=1: pad rows stay exact 0
            float s = p[1][0][r] + p[1][1][r];
            s += __shfl_xor(s, 1);
            s += __shfl_xor(s, 2);
            s += __shfl_xor(s, 4);
            s += __shfl_xor(s, 8);
            float rho = __builtin_amdgcn_rcpf(s + rowp1[r]) * rowm1[r];
            p[1][0][r] *= rho;
            p[1][1][r] *= rho;
        }
        // col normalize: sum over (mt,r) in-thread, then g-groups via shfl 16/32
        float t0 = ((p[0][0][0] + p[0][0][1]) + (p[0][0][2] + p[0][0][3]))
                 + ((p[1][0][0] + p[1][0][1]) + (p[1][0][2] + p[1][0][3]));
        float t1 = ((p[0][1][0] + p[0][1][1]) + (p[0][1][2] + p[0][1][3]))
                 + ((p[1][1][0] + p[1][1][1]) + (p[1][1][2] + p[1][1][3]));
        t0 += __shfl_xor(t0, 16);  t0 += __shfl_xor(t0, 32);
        t1 += __shfl_xor(t1, 16);  t1 += __shfl_xor(t1, 32);
        float rc0 = __builtin_amdgcn_rcpf(t0);                  // j0 < NN always
        float rc1 = __builtin_amdgcn_rcpf(t1 + colp1) * colm1;  // pad cols stay exact 0
        #pragma unroll
        for (int mt = 0; mt < 2; ++mt) {
            #pragma unroll
            for (int r = 0; r < 4; ++r) {
                p[mt][0][r] *= rc0;
                p[mt][1][r] *= rc1;
            }
        }
    }

    // ---- P8: store P straight from registers (16-lane contiguous runs) ----
    {
        float* ob = out + (size_t)b * (NN * NN);
        #pragma unroll
        for (int r = 0; r < 4; ++r) {           // mt=0 rows always valid
            int i = 4*g + r;
            ob[i * NN + c] = p[0][0][r];
            if ((16 + c) < NN) ob[i * NN + 16 + c] = p[0][1][r];
        }
        #pragma unroll
        for (int r = 0; r < 4; ++r) {           // mt=1 rows guarded
            int i = 16 + 4*g + r;
            if (i < NN) {
                ob[i * NN + c] = p[1][0][r];
                if ((16 + c) < NN) ob[i * NN + 16 + c] = p[1][1][r];
            }
        }
    }
}

extern "C" void kernel_launch(void* const* d_in, const int* in_sizes, int n_in,
                              void* d_out, int out_size, void* d_ws, size_t ws_size,
                              hipStream_t stream) {
    const float* A      = (const float*)d_in[0];
    const float* m      = (const float*)d_in[1];
    const float* tau_r  = (const float*)d_in[2];
    const float* ln1g   = (const float*)d_in[3];
    const float* ln1b   = (const float*)d_in[4];
    const float* W1     = (const float*)d_in[5];
    const float* b1     = (const float*)d_in[6];
    const float* W2     = (const float*)d_in[7];
    const float* b2     = (const float*)d_in[8];
    const float* ln2g   = (const float*)d_in[9];
    const float* ln2b   = (const float*)d_in[10];
    const float* protos = (const float*)d_in[11];
    float* out = (float*)d_out;

    const int B = in_sizes[0] / (NN * NN);

    _Float16* Bsw = (_Float16*)d_ws;                         // 16384 f16 = 32 KB
    _Float16* Asw = (_Float16*)((char*)d_ws + 32768);        //  4096 f16 =  8 KB

    k0_prep<<<8, 256, 0, stream>>>(W2, protos, Bsw, Asw);
    k1_mlp<<<B, 64, 0, stream>>>(A, m, tau_r, ln1g, ln1b, W1, b1, b2,
                                 ln2g, ln2b, Bsw, Asw, out);
}